// Round 13
// baseline (196.645 us; speedup 1.0000x reference)
//
#include <hip/hip_runtime.h>
#include <hip/hip_bf16.h>
#include <math.h>

// B=256, C=4, N=64, F=256, OC=8, OF=256
// d_out = out (256*2048 f32) then adj (256*4*256*256 f32).
// R13 = MEASUREMENT: k_pre x3 and k_gemm x3 (idempotent).
// pre+gemm = (dur - 108.5)/2 ; gaps = 49.5 - (pre+gemm).

typedef __bf16 bf16x8 __attribute__((ext_vector_type(8)));
typedef __bf16 bf16x4 __attribute__((ext_vector_type(4)));
typedef float f32x4 __attribute__((ext_vector_type(4)));

#define NB 256
#define NC 4
#define NN 64
#define NF 256
#define NO 2048

// ============ Kernel 1: s1, s2, Wc->bf16, x->zbf (2048 blocks, grid-stride) ==
__global__ __launch_bounds__(256) void k_pre(
    const float* __restrict__ x, const float* __restrict__ nb,
    const float* __restrict__ W1, const float* __restrict__ W2,
    const float* __restrict__ Wc,
    __hip_bfloat16* __restrict__ Wcb, __hip_bfloat16* __restrict__ zbf,
    float* __restrict__ s1, float* __restrict__ s2)
{
  __shared__ float w2s[256], w1s[256];
  int t = threadIdx.x;
  int w = t >> 6, l = t & 63;

  w2s[t] = W2[t] + W2[256 + t] + W2[512 + t] + W2[768 + t];
  w1s[t] = W1[t] + W1[256 + t] + W1[512 + t] + W1[768 + t];
  __syncthreads();

  int gw = blockIdx.x * 4 + w;
  float4 wv2 = *(const float4*)&w2s[l * 4];
  float4 wv1 = *(const float4*)&w1s[l * 4];
  for (int task = gw; task < 16640; task += 8192) {
    bool isS2 = task < 16384;
    const float4* src = isS2 ? ((const float4*)nb + (size_t)task * 256)
                             : ((const float4*)x + (size_t)(task - 16384) * 256);
    float4 wv = isS2 ? wv2 : wv1;
    float val = 0.f;
    #pragma unroll
    for (int k = 0; k < 4; ++k) {
      float4 v = src[l + 64 * k];
      val += v.x * wv.x + v.y * wv.y + v.z * wv.z + v.w * wv.w;
    }
    for (int off = 32; off > 0; off >>= 1) val += __shfl_down(val, off);
    if (l == 0) {
      if (isS2) s2[task] = val;
      else s1[task - 16384] = val;
    }
  }

  for (int task = blockIdx.x; task < 4352; task += 2048) {
    if (task < 4096) {
      int idx = task * 256 + t;
      float4 v = ((const float4*)Wc)[idx];
      bf16x4 o = { (__bf16)v.x, (__bf16)v.y, (__bf16)v.z, (__bf16)v.w };
      ((bf16x4*)Wcb)[idx] = o;
    } else {
      int i = (task - 4096) * 256 + t;
      int e = i * 4;
      int b = e >> 10, r = e & 1023;
      float4 v = ((const float4*)x)[i];
      bf16x4 o = { (__bf16)v.x, (__bf16)v.y, (__bf16)v.z, (__bf16)v.w };
      *(bf16x4*)(zbf + (size_t)b * 2048 + 1024 + r) = o;
    }
  }
}

// ============ Kernel 2: adj + h (R5 structure, nt stores) ============
__global__ __launch_bounds__(256) void k_adj(
    const float* __restrict__ x, const float* __restrict__ nb,
    const float* __restrict__ s1, const float* __restrict__ s2,
    float* __restrict__ adj, __hip_bfloat16* __restrict__ zbf)
{
  __shared__ float xs[256], ns[256], invs[256], wsh[64];
  __shared__ float part[4][256];
  int t = threadIdx.x;
  int w = t >> 6, l = t & 63;
  int blk = blockIdx.x;
  int b = blk >> 2, c = blk & 3;

  if (t < 64) {
    float v = s1[b] * s2[b * 64 + t];
    float m = v;
    for (int off = 32; off > 0; off >>= 1) m = fmaxf(m, __shfl_xor(m, off));
    float e = expf(v - m);
    float s = e;
    for (int off = 32; off > 0; off >>= 1) s += __shfl_xor(s, off);
    wsh[t] = e / s;
  }
  xs[t] = x[(size_t)blk * 256 + t];
  __syncthreads();

  const float4* nb4 = (const float4*)(nb + (size_t)b * 65536 + c * 256);
  float4 a4 = {0.f, 0.f, 0.f, 0.f};
  #pragma unroll
  for (int k = 0; k < 16; ++k) {
    int n = w + 4 * k;
    float4 v = nb4[(size_t)n * 256 + l];
    float wn = wsh[n];
    a4.x = fmaf(wn, v.x, a4.x);
    a4.y = fmaf(wn, v.y, a4.y);
    a4.z = fmaf(wn, v.z, a4.z);
    a4.w = fmaf(wn, v.w, a4.w);
  }
  *(float4*)&part[w][l * 4] = a4;
  __syncthreads();
  ns[t] = part[0][t] + part[1][t] + part[2][t] + part[3][t];
  __syncthreads();

  int j0 = l * 4;
  float4 xv = *(const float4*)&xs[j0];
  float4 nv = *(const float4*)&ns[j0];
  int i0 = w * 64;

  float4 cs = {0.f, 0.f, 0.f, 0.f};
  #pragma unroll 4
  for (int ii = 0; ii < 64; ++ii) {
    int i = i0 + ii;
    float xi = xs[i], ni = ns[i];
    cs.x += __builtin_amdgcn_sqrtf(fmaxf(fabsf(fmaf(xi, nv.x, xv.x * ni)), 1e-8f));
    cs.y += __builtin_amdgcn_sqrtf(fmaxf(fabsf(fmaf(xi, nv.y, xv.y * ni)), 1e-8f));
    cs.z += __builtin_amdgcn_sqrtf(fmaxf(fabsf(fmaf(xi, nv.z, xv.z * ni)), 1e-8f));
    cs.w += __builtin_amdgcn_sqrtf(fmaxf(fabsf(fmaf(xi, nv.w, xv.w * ni)), 1e-8f));
  }
  *(float4*)&part[w][j0] = cs;
  __syncthreads();
  invs[t] = 1.f / (part[0][t] + part[1][t] + part[2][t] + part[3][t] + 1e-7f);
  __syncthreads();

  float4 iv = *(const float4*)&invs[j0];
  float4 ha = {0.f, 0.f, 0.f, 0.f};
  float* ab = adj + (size_t)blk * 65536;
  #pragma unroll 4
  for (int ii = 0; ii < 64; ++ii) {
    int i = i0 + ii;
    float xi = xs[i], ni = ns[i];
    float pix = invs[i] * xi;
    float v0 = fmaf(xi, nv.x, xv.x * ni);
    float v1 = fmaf(xi, nv.y, xv.y * ni);
    float v2 = fmaf(xi, nv.z, xv.z * ni);
    float v3 = fmaf(xi, nv.w, xv.w * ni);
    float g0 = copysignf(__builtin_amdgcn_sqrtf(fmaxf(fabsf(v0), 1e-8f)), v0);
    float g1 = copysignf(__builtin_amdgcn_sqrtf(fmaxf(fabsf(v1), 1e-8f)), v1);
    float g2 = copysignf(__builtin_amdgcn_sqrtf(fmaxf(fabsf(v2), 1e-8f)), v2);
    float g3 = copysignf(__builtin_amdgcn_sqrtf(fmaxf(fabsf(v3), 1e-8f)), v3);
    f32x4 o = { g0 * iv.x, g1 * iv.y, g2 * iv.z, g3 * iv.w };
    __builtin_nontemporal_store(o, (f32x4*)&ab[(size_t)i * 256 + j0]);
    ha.x = fmaf(g0, pix, ha.x);
    ha.y = fmaf(g1, pix, ha.y);
    ha.z = fmaf(g2, pix, ha.z);
    ha.w = fmaf(g3, pix, ha.w);
  }
  __syncthreads();
  *(float4*)&part[w][j0] = ha;
  __syncthreads();
  float hsum = part[0][t] + part[1][t] + part[2][t] + part[3][t];
  zbf[(size_t)b * 2048 + c * 256 + t] = __float2bfloat16(hsum);
}

// ============ Kernel 3: out = Z @ Wc^T (bf16 MFMA, XCD-grouped) ============
__global__ __launch_bounds__(256) void k_gemm(
    const __hip_bfloat16* __restrict__ zb, const __hip_bfloat16* __restrict__ Wcb,
    float* __restrict__ out)
{
  int tid = threadIdx.x;
  int wave = tid >> 6, lane = tid & 63;
  int g = lane >> 4, r = lane & 15;
  int id = blockIdx.x;
  int bm = (id >> 3) & 7;
  int bn = (id & 7) * 8 + (id >> 6);
  int m0 = bm * 32 + (wave & 1) * 16;
  int n0 = bn * 32 + (wave >> 1) * 16;

  const bf16x8* pa = (const bf16x8*)(zb  + (size_t)(m0 + r) * 2048 + g * 8);
  const bf16x8* pw = (const bf16x8*)(Wcb + (size_t)(n0 + r) * 2048 + g * 8);

  f32x4 acc0 = {0.f, 0.f, 0.f, 0.f}, acc1 = {0.f, 0.f, 0.f, 0.f};
  #pragma unroll 4
  for (int ks = 0; ks < 64; ks += 2) {
    bf16x8 a0 = pa[ks * 4];
    bf16x8 b0 = pw[ks * 4];
    bf16x8 a1 = pa[ks * 4 + 4];
    bf16x8 b1 = pw[ks * 4 + 4];
    acc0 = __builtin_amdgcn_mfma_f32_16x16x32_bf16(a0, b0, acc0, 0, 0, 0);
    acc1 = __builtin_amdgcn_mfma_f32_16x16x32_bf16(a1, b1, acc1, 0, 0, 0);
  }
  acc0 += acc1;
  #pragma unroll
  for (int q = 0; q < 4; ++q) {
    int row = m0 + g * 4 + q;
    __builtin_nontemporal_store(acc0[q], &out[(size_t)row * 2048 + n0 + r]);
  }
}

// ================= Fallback path (small ws) =================
__global__ __launch_bounds__(256) void k_scores_fb(
    const float* __restrict__ x, const float* __restrict__ nb,
    const float* __restrict__ W1, const float* __restrict__ W2,
    float* __restrict__ s1, float* __restrict__ s2)
{
  __shared__ float red[4];
  int t = threadIdx.x;
  int gid = blockIdx.x;
  float val;
  if (gid < NB * NN) {
    float w = W2[t] + W2[256 + t] + W2[512 + t] + W2[768 + t];
    const float* p = nb + (size_t)gid * 1024;
    val = w * (p[t] + p[256 + t] + p[512 + t] + p[768 + t]);
  } else {
    int b = gid - NB * NN;
    float w = W1[t] + W1[256 + t] + W1[512 + t] + W1[768 + t];
    const float* p = x + (size_t)b * 1024;
    val = w * (p[t] + p[256 + t] + p[512 + t] + p[768 + t]);
  }
  for (int off = 32; off > 0; off >>= 1) val += __shfl_down(val, off);
  if ((t & 63) == 0) red[t >> 6] = val;
  __syncthreads();
  if (t == 0) {
    float s = red[0] + red[1] + red[2] + red[3];
    if (gid < NB * NN) s2[gid] = s;
    else s1[gid - NB * NN] = s;
  }
}

__global__ __launch_bounds__(256) void k_adj_fb(
    const float* __restrict__ x, const float* __restrict__ nb,
    const float* __restrict__ s1, const float* __restrict__ s2,
    float* __restrict__ adj, float* __restrict__ hf)
{
  __shared__ float xs[256], ns[256], invs[256], wsh[64];
  __shared__ float part[4][256];
  int t = threadIdx.x;
  int w = t >> 6, l = t & 63;
  int blk = blockIdx.x;
  int b = blk >> 2, c = blk & 3;

  if (t < 64) {
    float v = s1[b] * s2[b * 64 + t];
    float m = v;
    for (int off = 32; off > 0; off >>= 1) m = fmaxf(m, __shfl_xor(m, off));
    float e = expf(v - m);
    float s = e;
    for (int off = 32; off > 0; off >>= 1) s += __shfl_xor(s, off);
    wsh[t] = e / s;
  }
  __syncthreads();
  float acc = 0.f;
  const float* pb = nb + (size_t)b * 65536 + c * 256 + t;
  #pragma unroll 8
  for (int n = 0; n < 64; ++n) acc = fmaf(wsh[n], pb[(size_t)n * 1024], acc);
  ns[t] = acc;
  xs[t] = x[(size_t)blk * 256 + t];
  __syncthreads();

  int j0 = l * 4;
  float4 xv = *(const float4*)&xs[j0];
  float4 nv = *(const float4*)&ns[j0];
  int i0 = w * 64;
  float4 cs = {0.f, 0.f, 0.f, 0.f};
  for (int ii = 0; ii < 64; ++ii) {
    int i = i0 + ii;
    float xi = xs[i], ni = ns[i];
    cs.x += __builtin_amdgcn_sqrtf(fmaxf(fabsf(fmaf(xi, nv.x, xv.x * ni)), 1e-8f));
    cs.y += __builtin_amdgcn_sqrtf(fmaxf(fabsf(fmaf(xi, nv.y, xv.y * ni)), 1e-8f));
    cs.z += __builtin_amdgcn_sqrtf(fmaxf(fabsf(fmaf(xi, nv.z, xv.z * ni)), 1e-8f));
    cs.w += __builtin_amdgcn_sqrtf(fmaxf(fabsf(fmaf(xi, nv.w, xv.w * ni)), 1e-8f));
  }
  *(float4*)&part[w][j0] = cs;
  __syncthreads();
  invs[t] = 1.f / (part[0][t] + part[1][t] + part[2][t] + part[3][t] + 1e-7f);
  __syncthreads();

  float4 iv = *(const float4*)&invs[j0];
  float4 ha = {0.f, 0.f, 0.f, 0.f};
  float* ab = adj + (size_t)blk * 65536;
  for (int ii = 0; ii < 64; ++ii) {
    int i = i0 + ii;
    float xi = xs[i], ni = ns[i];
    float pix = invs[i] * xi;
    float v0 = fmaf(xi, nv.x, xv.x * ni);
    float v1 = fmaf(xi, nv.y, xv.y * ni);
    float v2 = fmaf(xi, nv.z, xv.z * ni);
    float v3 = fmaf(xi, nv.w, xv.w * ni);
    float g0 = copysignf(__builtin_amdgcn_sqrtf(fmaxf(fabsf(v0), 1e-8f)), v0);
    float g1 = copysignf(__builtin_amdgcn_sqrtf(fmaxf(fabsf(v1), 1e-8f)), v1);
    float g2 = copysignf(__builtin_amdgcn_sqrtf(fmaxf(fabsf(v2), 1e-8f)), v2);
    float g3 = copysignf(__builtin_amdgcn_sqrtf(fmaxf(fabsf(v3), 1e-8f)), v3);
    f32x4 o = { g0 * iv.x, g1 * iv.y, g2 * iv.z, g3 * iv.w };
    *(f32x4*)&ab[(size_t)i * 256 + j0] = o;
    ha.x = fmaf(g0, pix, ha.x);
    ha.y = fmaf(g1, pix, ha.y);
    ha.z = fmaf(g2, pix, ha.z);
    ha.w = fmaf(g3, pix, ha.w);
  }
  __syncthreads();
  *(float4*)&part[w][j0] = ha;
  __syncthreads();
  hf[(size_t)blk * 256 + t] = part[0][t] + part[1][t] + part[2][t] + part[3][t];
}

__device__ inline bf16x8 cvt8_p(const float* p) {
  const float4* q = reinterpret_cast<const float4*>(p);
  float4 a = q[0], bq = q[1];
  bf16x8 r;
  r[0] = (__bf16)a.x;  r[1] = (__bf16)a.y;  r[2] = (__bf16)a.z;  r[3] = (__bf16)a.w;
  r[4] = (__bf16)bq.x; r[5] = (__bf16)bq.y; r[6] = (__bf16)bq.z; r[7] = (__bf16)bq.w;
  return r;
}

__global__ __launch_bounds__(256) void k_gemm_f32(
    const float* __restrict__ h, const float* __restrict__ x,
    const float* __restrict__ Wc, float* __restrict__ out)
{
  int tid = threadIdx.x;
  int wave = tid >> 6, lane = tid & 63;
  int g = lane >> 4, r = lane & 15;
  int bm = blockIdx.x & 3, bn = blockIdx.x >> 2;
  int m0 = bm * 64 + wave * 16;
  int n0 = bn * 32;
  int arow = m0 + r;
  int koff = g * 8;

  const float* za = h + (size_t)arow * 1024 + koff;
  const float* zb = x + (size_t)arow * 1024 + koff;
  const float* w0 = Wc + (size_t)(n0 + r) * 2048 + koff;
  const float* w1 = Wc + (size_t)(n0 + 16 + r) * 2048 + koff;

  f32x4 acc0 = {0.f, 0.f, 0.f, 0.f}, acc1 = {0.f, 0.f, 0.f, 0.f};
  #pragma unroll 4
  for (int ks = 0; ks < 32; ++ks) {
    acc0 = __builtin_amdgcn_mfma_f32_16x16x32_bf16(cvt8_p(za + ks * 32), cvt8_p(w0 + ks * 32), acc0, 0, 0, 0);
    acc1 = __builtin_amdgcn_mfma_f32_16x16x32_bf16(cvt8_p(za + ks * 32), cvt8_p(w1 + ks * 32), acc1, 0, 0, 0);
  }
  #pragma unroll 4
  for (int ks = 0; ks < 32; ++ks) {
    acc0 = __builtin_amdgcn_mfma_f32_16x16x32_bf16(cvt8_p(zb + ks * 32), cvt8_p(w0 + 1024 + ks * 32), acc0, 0, 0, 0);
    acc1 = __builtin_amdgcn_mfma_f32_16x16x32_bf16(cvt8_p(zb + ks * 32), cvt8_p(w1 + 1024 + ks * 32), acc1, 0, 0, 0);
  }
  #pragma unroll
  for (int q = 0; q < 4; ++q) {
    int row = m0 + g * 4 + q;
    out[(size_t)row * 2048 + n0 + r]      = acc0[q];
    out[(size_t)row * 2048 + n0 + 16 + r] = acc1[q];
  }
}

extern "C" void kernel_launch(void* const* d_in, const int* in_sizes, int n_in,
                              void* d_out, int out_size, void* d_ws, size_t ws_size,
                              hipStream_t stream) {
  const float* x  = (const float*)d_in[0];
  const float* nb = (const float*)d_in[1];
  const float* W1 = (const float*)d_in[2];
  const float* W2 = (const float*)d_in[3];
  const float* Wc = (const float*)d_in[4];
  float* out = (float*)d_out;
  float* adj = out + (size_t)NB * NO;

  char* ws = (char*)d_ws;
  const size_t ZBF_B = 1048576;        // 256*2048 bf16
  const size_t WCB_B = 8388608;        // 2048*2048 bf16
  const size_t FREG = (256 + 16384) * 4;
  bool fast = ws_size >= ZBF_B + WCB_B + FREG;

  if (fast) {
    __hip_bfloat16* zbf = (__hip_bfloat16*)ws;
    __hip_bfloat16* Wcb = (__hip_bfloat16*)(ws + ZBF_B);
    float* s1  = (float*)(ws + ZBF_B + WCB_B);
    float* s2  = s1 + 256;
    // MEASUREMENT: 3x k_pre, 1x k_adj, 3x k_gemm (all idempotent).
    k_pre<<<2048, 256, 0, stream>>>(x, nb, W1, W2, Wc, Wcb, zbf, s1, s2);
    k_pre<<<2048, 256, 0, stream>>>(x, nb, W1, W2, Wc, Wcb, zbf, s1, s2);
    k_pre<<<2048, 256, 0, stream>>>(x, nb, W1, W2, Wc, Wcb, zbf, s1, s2);
    k_adj<<<NB * NC, 256, 0, stream>>>(x, nb, s1, s2, adj, zbf);
    k_gemm<<<512, 256, 0, stream>>>(zbf, Wcb, out);
    k_gemm<<<512, 256, 0, stream>>>(zbf, Wcb, out);
    k_gemm<<<512, 256, 0, stream>>>(zbf, Wcb, out);
  } else {
    float* hws = (float*)d_ws;
    float* s1  = hws + 262144;
    float* s2  = s1 + 256;
    k_scores_fb<<<NB * NN + NB, 256, 0, stream>>>(x, nb, W1, W2, s1, s2);
    k_adj_fb<<<NB * NC, 256, 0, stream>>>(x, nb, s1, s2, adj, hws);
    k_gemm_f32<<<256, 256, 0, stream>>>(hws, x, Wc, out);
  }
}

// Round 14
// 108.860 us; speedup vs baseline: 1.8064x; 1.8064x over previous
//
#include <hip/hip_runtime.h>
#include <hip/hip_bf16.h>
#include <math.h>

// B=256, C=4, N=64, F=256, OC=8, OF=256
// d_out = out (256*2048 f32) then adj (256*4*256*256 f32).
// R14: k_gemm K-split across waves (16x32 tile, 4 waves, LDS reduce) -> 16 waves/CU.

typedef __bf16 bf16x8 __attribute__((ext_vector_type(8)));
typedef __bf16 bf16x4 __attribute__((ext_vector_type(4)));
typedef float f32x4 __attribute__((ext_vector_type(4)));

#define NB 256
#define NC 4
#define NN 64
#define NF 256
#define NO 2048

// ============ Kernel 1: s1, s2, Wc->bf16, x->zbf (2048 blocks, grid-stride) ==
__global__ __launch_bounds__(256) void k_pre(
    const float* __restrict__ x, const float* __restrict__ nb,
    const float* __restrict__ W1, const float* __restrict__ W2,
    const float* __restrict__ Wc,
    __hip_bfloat16* __restrict__ Wcb, __hip_bfloat16* __restrict__ zbf,
    float* __restrict__ s1, float* __restrict__ s2)
{
  __shared__ float w2s[256], w1s[256];
  int t = threadIdx.x;
  int w = t >> 6, l = t & 63;

  w2s[t] = W2[t] + W2[256 + t] + W2[512 + t] + W2[768 + t];
  w1s[t] = W1[t] + W1[256 + t] + W1[512 + t] + W1[768 + t];
  __syncthreads();

  int gw = blockIdx.x * 4 + w;
  float4 wv2 = *(const float4*)&w2s[l * 4];
  float4 wv1 = *(const float4*)&w1s[l * 4];
  for (int task = gw; task < 16640; task += 8192) {
    bool isS2 = task < 16384;
    const float4* src = isS2 ? ((const float4*)nb + (size_t)task * 256)
                             : ((const float4*)x + (size_t)(task - 16384) * 256);
    float4 wv = isS2 ? wv2 : wv1;
    float val = 0.f;
    #pragma unroll
    for (int k = 0; k < 4; ++k) {
      float4 v = src[l + 64 * k];
      val += v.x * wv.x + v.y * wv.y + v.z * wv.z + v.w * wv.w;
    }
    for (int off = 32; off > 0; off >>= 1) val += __shfl_down(val, off);
    if (l == 0) {
      if (isS2) s2[task] = val;
      else s1[task - 16384] = val;
    }
  }

  for (int task = blockIdx.x; task < 4352; task += 2048) {
    if (task < 4096) {
      int idx = task * 256 + t;
      float4 v = ((const float4*)Wc)[idx];
      bf16x4 o = { (__bf16)v.x, (__bf16)v.y, (__bf16)v.z, (__bf16)v.w };
      ((bf16x4*)Wcb)[idx] = o;
    } else {
      int i = (task - 4096) * 256 + t;
      int e = i * 4;
      int b = e >> 10, r = e & 1023;
      float4 v = ((const float4*)x)[i];
      bf16x4 o = { (__bf16)v.x, (__bf16)v.y, (__bf16)v.z, (__bf16)v.w };
      *(bf16x4*)(zbf + (size_t)b * 2048 + 1024 + r) = o;
    }
  }
}

// ============ Kernel 2: adj + h (R5 structure, nt stores) ============
__global__ __launch_bounds__(256) void k_adj(
    const float* __restrict__ x, const float* __restrict__ nb,
    const float* __restrict__ s1, const float* __restrict__ s2,
    float* __restrict__ adj, __hip_bfloat16* __restrict__ zbf)
{
  __shared__ float xs[256], ns[256], invs[256], wsh[64];
  __shared__ float part[4][256];
  int t = threadIdx.x;
  int w = t >> 6, l = t & 63;
  int blk = blockIdx.x;
  int b = blk >> 2, c = blk & 3;

  if (t < 64) {
    float v = s1[b] * s2[b * 64 + t];
    float m = v;
    for (int off = 32; off > 0; off >>= 1) m = fmaxf(m, __shfl_xor(m, off));
    float e = expf(v - m);
    float s = e;
    for (int off = 32; off > 0; off >>= 1) s += __shfl_xor(s, off);
    wsh[t] = e / s;
  }
  xs[t] = x[(size_t)blk * 256 + t];
  __syncthreads();

  const float4* nb4 = (const float4*)(nb + (size_t)b * 65536 + c * 256);
  float4 a4 = {0.f, 0.f, 0.f, 0.f};
  #pragma unroll
  for (int k = 0; k < 16; ++k) {
    int n = w + 4 * k;
    float4 v = nb4[(size_t)n * 256 + l];
    float wn = wsh[n];
    a4.x = fmaf(wn, v.x, a4.x);
    a4.y = fmaf(wn, v.y, a4.y);
    a4.z = fmaf(wn, v.z, a4.z);
    a4.w = fmaf(wn, v.w, a4.w);
  }
  *(float4*)&part[w][l * 4] = a4;
  __syncthreads();
  ns[t] = part[0][t] + part[1][t] + part[2][t] + part[3][t];
  __syncthreads();

  int j0 = l * 4;
  float4 xv = *(const float4*)&xs[j0];
  float4 nv = *(const float4*)&ns[j0];
  int i0 = w * 64;

  float4 cs = {0.f, 0.f, 0.f, 0.f};
  #pragma unroll 4
  for (int ii = 0; ii < 64; ++ii) {
    int i = i0 + ii;
    float xi = xs[i], ni = ns[i];
    cs.x += __builtin_amdgcn_sqrtf(fmaxf(fabsf(fmaf(xi, nv.x, xv.x * ni)), 1e-8f));
    cs.y += __builtin_amdgcn_sqrtf(fmaxf(fabsf(fmaf(xi, nv.y, xv.y * ni)), 1e-8f));
    cs.z += __builtin_amdgcn_sqrtf(fmaxf(fabsf(fmaf(xi, nv.z, xv.z * ni)), 1e-8f));
    cs.w += __builtin_amdgcn_sqrtf(fmaxf(fabsf(fmaf(xi, nv.w, xv.w * ni)), 1e-8f));
  }
  *(float4*)&part[w][j0] = cs;
  __syncthreads();
  invs[t] = 1.f / (part[0][t] + part[1][t] + part[2][t] + part[3][t] + 1e-7f);
  __syncthreads();

  float4 iv = *(const float4*)&invs[j0];
  float4 ha = {0.f, 0.f, 0.f, 0.f};
  float* ab = adj + (size_t)blk * 65536;
  #pragma unroll 4
  for (int ii = 0; ii < 64; ++ii) {
    int i = i0 + ii;
    float xi = xs[i], ni = ns[i];
    float pix = invs[i] * xi;
    float v0 = fmaf(xi, nv.x, xv.x * ni);
    float v1 = fmaf(xi, nv.y, xv.y * ni);
    float v2 = fmaf(xi, nv.z, xv.z * ni);
    float v3 = fmaf(xi, nv.w, xv.w * ni);
    float g0 = copysignf(__builtin_amdgcn_sqrtf(fmaxf(fabsf(v0), 1e-8f)), v0);
    float g1 = copysignf(__builtin_amdgcn_sqrtf(fmaxf(fabsf(v1), 1e-8f)), v1);
    float g2 = copysignf(__builtin_amdgcn_sqrtf(fmaxf(fabsf(v2), 1e-8f)), v2);
    float g3 = copysignf(__builtin_amdgcn_sqrtf(fmaxf(fabsf(v3), 1e-8f)), v3);
    f32x4 o = { g0 * iv.x, g1 * iv.y, g2 * iv.z, g3 * iv.w };
    __builtin_nontemporal_store(o, (f32x4*)&ab[(size_t)i * 256 + j0]);
    ha.x = fmaf(g0, pix, ha.x);
    ha.y = fmaf(g1, pix, ha.y);
    ha.z = fmaf(g2, pix, ha.z);
    ha.w = fmaf(g3, pix, ha.w);
  }
  __syncthreads();
  *(float4*)&part[w][j0] = ha;
  __syncthreads();
  float hsum = part[0][t] + part[1][t] + part[2][t] + part[3][t];
  zbf[(size_t)b * 2048 + c * 256 + t] = __float2bfloat16(hsum);
}

// ============ Kernel 3: out = Z @ Wc^T — K-split across waves ============
// 1024 blocks x 256 thr. Block: 16(m) x 32(n) tile. Wave w: kh=w>>1 (K half),
// nh=w&1 (n half 16). kh=1 waves write partials to LDS; kh=0 waves add+store.
__global__ __launch_bounds__(256) void k_gemm(
    const __hip_bfloat16* __restrict__ zb, const __hip_bfloat16* __restrict__ Wcb,
    float* __restrict__ out)
{
  __shared__ float red[2][16][17];
  int tid = threadIdx.x;
  int wave = tid >> 6, lane = tid & 63;
  int g = lane >> 4, r = lane & 15;
  int id = blockIdx.x;
  int bm = id & 15, bn = id >> 4;
  int kh = wave >> 1, nh = wave & 1;
  int m0 = bm * 16;
  int n0 = bn * 32 + nh * 16;

  const bf16x8* pa = (const bf16x8*)(zb  + (size_t)(m0 + r) * 2048 + kh * 1024 + g * 8);
  const bf16x8* pw = (const bf16x8*)(Wcb + (size_t)(n0 + r) * 2048 + kh * 1024 + g * 8);

  f32x4 acc0 = {0.f, 0.f, 0.f, 0.f}, acc1 = {0.f, 0.f, 0.f, 0.f};
  #pragma unroll 4
  for (int ks = 0; ks < 32; ks += 2) {
    bf16x8 a0 = pa[ks * 4];
    bf16x8 b0 = pw[ks * 4];
    bf16x8 a1 = pa[ks * 4 + 4];
    bf16x8 b1 = pw[ks * 4 + 4];
    acc0 = __builtin_amdgcn_mfma_f32_16x16x32_bf16(a0, b0, acc0, 0, 0, 0);
    acc1 = __builtin_amdgcn_mfma_f32_16x16x32_bf16(a1, b1, acc1, 0, 0, 0);
  }
  acc0 += acc1;

  if (kh == 1) {
    #pragma unroll
    for (int q = 0; q < 4; ++q) red[nh][g * 4 + q][r] = acc0[q];
  }
  __syncthreads();
  if (kh == 0) {
    #pragma unroll
    for (int q = 0; q < 4; ++q) {
      int row = m0 + g * 4 + q;
      __builtin_nontemporal_store(acc0[q] + red[nh][g * 4 + q][r],
                                  &out[(size_t)row * 2048 + n0 + r]);
    }
  }
}

// ================= Fallback path (small ws) =================
__global__ __launch_bounds__(256) void k_scores_fb(
    const float* __restrict__ x, const float* __restrict__ nb,
    const float* __restrict__ W1, const float* __restrict__ W2,
    float* __restrict__ s1, float* __restrict__ s2)
{
  __shared__ float red[4];
  int t = threadIdx.x;
  int gid = blockIdx.x;
  float val;
  if (gid < NB * NN) {
    float w = W2[t] + W2[256 + t] + W2[512 + t] + W2[768 + t];
    const float* p = nb + (size_t)gid * 1024;
    val = w * (p[t] + p[256 + t] + p[512 + t] + p[768 + t]);
  } else {
    int b = gid - NB * NN;
    float w = W1[t] + W1[256 + t] + W1[512 + t] + W1[768 + t];
    const float* p = x + (size_t)b * 1024;
    val = w * (p[t] + p[256 + t] + p[512 + t] + p[768 + t]);
  }
  for (int off = 32; off > 0; off >>= 1) val += __shfl_down(val, off);
  if ((t & 63) == 0) red[t >> 6] = val;
  __syncthreads();
  if (t == 0) {
    float s = red[0] + red[1] + red[2] + red[3];
    if (gid < NB * NN) s2[gid] = s;
    else s1[gid - NB * NN] = s;
  }
}

__global__ __launch_bounds__(256) void k_adj_fb(
    const float* __restrict__ x, const float* __restrict__ nb,
    const float* __restrict__ s1, const float* __restrict__ s2,
    float* __restrict__ adj, float* __restrict__ hf)
{
  __shared__ float xs[256], ns[256], invs[256], wsh[64];
  __shared__ float part[4][256];
  int t = threadIdx.x;
  int w = t >> 6, l = t & 63;
  int blk = blockIdx.x;
  int b = blk >> 2, c = blk & 3;

  if (t < 64) {
    float v = s1[b] * s2[b * 64 + t];
    float m = v;
    for (int off = 32; off > 0; off >>= 1) m = fmaxf(m, __shfl_xor(m, off));
    float e = expf(v - m);
    float s = e;
    for (int off = 32; off > 0; off >>= 1) s += __shfl_xor(s, off);
    wsh[t] = e / s;
  }
  __syncthreads();
  float acc = 0.f;
  const float* pb = nb + (size_t)b * 65536 + c * 256 + t;
  #pragma unroll 8
  for (int n = 0; n < 64; ++n) acc = fmaf(wsh[n], pb[(size_t)n * 1024], acc);
  ns[t] = acc;
  xs[t] = x[(size_t)blk * 256 + t];
  __syncthreads();

  int j0 = l * 4;
  float4 xv = *(const float4*)&xs[j0];
  float4 nv = *(const float4*)&ns[j0];
  int i0 = w * 64;
  float4 cs = {0.f, 0.f, 0.f, 0.f};
  for (int ii = 0; ii < 64; ++ii) {
    int i = i0 + ii;
    float xi = xs[i], ni = ns[i];
    cs.x += __builtin_amdgcn_sqrtf(fmaxf(fabsf(fmaf(xi, nv.x, xv.x * ni)), 1e-8f));
    cs.y += __builtin_amdgcn_sqrtf(fmaxf(fabsf(fmaf(xi, nv.y, xv.y * ni)), 1e-8f));
    cs.z += __builtin_amdgcn_sqrtf(fmaxf(fabsf(fmaf(xi, nv.z, xv.z * ni)), 1e-8f));
    cs.w += __builtin_amdgcn_sqrtf(fmaxf(fabsf(fmaf(xi, nv.w, xv.w * ni)), 1e-8f));
  }
  *(float4*)&part[w][j0] = cs;
  __syncthreads();
  invs[t] = 1.f / (part[0][t] + part[1][t] + part[2][t] + part[3][t] + 1e-7f);
  __syncthreads();

  float4 iv = *(const float4*)&invs[j0];
  float4 ha = {0.f, 0.f, 0.f, 0.f};
  float* ab = adj + (size_t)blk * 65536;
  for (int ii = 0; ii < 64; ++ii) {
    int i = i0 + ii;
    float xi = xs[i], ni = ns[i];
    float pix = invs[i] * xi;
    float v0 = fmaf(xi, nv.x, xv.x * ni);
    float v1 = fmaf(xi, nv.y, xv.y * ni);
    float v2 = fmaf(xi, nv.z, xv.z * ni);
    float v3 = fmaf(xi, nv.w, xv.w * ni);
    float g0 = copysignf(__builtin_amdgcn_sqrtf(fmaxf(fabsf(v0), 1e-8f)), v0);
    float g1 = copysignf(__builtin_amdgcn_sqrtf(fmaxf(fabsf(v1), 1e-8f)), v1);
    float g2 = copysignf(__builtin_amdgcn_sqrtf(fmaxf(fabsf(v2), 1e-8f)), v2);
    float g3 = copysignf(__builtin_amdgcn_sqrtf(fmaxf(fabsf(v3), 1e-8f)), v3);
    f32x4 o = { g0 * iv.x, g1 * iv.y, g2 * iv.z, g3 * iv.w };
    *(f32x4*)&ab[(size_t)i * 256 + j0] = o;
    ha.x = fmaf(g0, pix, ha.x);
    ha.y = fmaf(g1, pix, ha.y);
    ha.z = fmaf(g2, pix, ha.z);
    ha.w = fmaf(g3, pix, ha.w);
  }
  __syncthreads();
  *(float4*)&part[w][j0] = ha;
  __syncthreads();
  hf[(size_t)blk * 256 + t] = part[0][t] + part[1][t] + part[2][t] + part[3][t];
}

__device__ inline bf16x8 cvt8_p(const float* p) {
  const float4* q = reinterpret_cast<const float4*>(p);
  float4 a = q[0], bq = q[1];
  bf16x8 r;
  r[0] = (__bf16)a.x;  r[1] = (__bf16)a.y;  r[2] = (__bf16)a.z;  r[3] = (__bf16)a.w;
  r[4] = (__bf16)bq.x; r[5] = (__bf16)bq.y; r[6] = (__bf16)bq.z; r[7] = (__bf16)bq.w;
  return r;
}

__global__ __launch_bounds__(256) void k_gemm_f32(
    const float* __restrict__ h, const float* __restrict__ x,
    const float* __restrict__ Wc, float* __restrict__ out)
{
  int tid = threadIdx.x;
  int wave = tid >> 6, lane = tid & 63;
  int g = lane >> 4, r = lane & 15;
  int bm = blockIdx.x & 3, bn = blockIdx.x >> 2;
  int m0 = bm * 64 + wave * 16;
  int n0 = bn * 32;
  int arow = m0 + r;
  int koff = g * 8;

  const float* za = h + (size_t)arow * 1024 + koff;
  const float* zb = x + (size_t)arow * 1024 + koff;
  const float* w0 = Wc + (size_t)(n0 + r) * 2048 + koff;
  const float* w1 = Wc + (size_t)(n0 + 16 + r) * 2048 + koff;

  f32x4 acc0 = {0.f, 0.f, 0.f, 0.f}, acc1 = {0.f, 0.f, 0.f, 0.f};
  #pragma unroll 4
  for (int ks = 0; ks < 32; ++ks) {
    acc0 = __builtin_amdgcn_mfma_f32_16x16x32_bf16(cvt8_p(za + ks * 32), cvt8_p(w0 + ks * 32), acc0, 0, 0, 0);
    acc1 = __builtin_amdgcn_mfma_f32_16x16x32_bf16(cvt8_p(za + ks * 32), cvt8_p(w1 + ks * 32), acc1, 0, 0, 0);
  }
  #pragma unroll 4
  for (int ks = 0; ks < 32; ++ks) {
    acc0 = __builtin_amdgcn_mfma_f32_16x16x32_bf16(cvt8_p(zb + ks * 32), cvt8_p(w0 + 1024 + ks * 32), acc0, 0, 0, 0);
    acc1 = __builtin_amdgcn_mfma_f32_16x16x32_bf16(cvt8_p(zb + ks * 32), cvt8_p(w1 + 1024 + ks * 32), acc1, 0, 0, 0);
  }
  #pragma unroll
  for (int q = 0; q < 4; ++q) {
    int row = m0 + g * 4 + q;
    out[(size_t)row * 2048 + n0 + r]      = acc0[q];
    out[(size_t)row * 2048 + n0 + 16 + r] = acc1[q];
  }
}

extern "C" void kernel_launch(void* const* d_in, const int* in_sizes, int n_in,
                              void* d_out, int out_size, void* d_ws, size_t ws_size,
                              hipStream_t stream) {
  const float* x  = (const float*)d_in[0];
  const float* nb = (const float*)d_in[1];
  const float* W1 = (const float*)d_in[2];
  const float* W2 = (const float*)d_in[3];
  const float* Wc = (const float*)d_in[4];
  float* out = (float*)d_out;
  float* adj = out + (size_t)NB * NO;

  char* ws = (char*)d_ws;
  const size_t ZBF_B = 1048576;        // 256*2048 bf16
  const size_t WCB_B = 8388608;        // 2048*2048 bf16
  const size_t FREG = (256 + 16384) * 4;
  bool fast = ws_size >= ZBF_B + WCB_B + FREG;

  if (fast) {
    __hip_bfloat16* zbf = (__hip_bfloat16*)ws;
    __hip_bfloat16* Wcb = (__hip_bfloat16*)(ws + ZBF_B);
    float* s1  = (float*)(ws + ZBF_B + WCB_B);
    float* s2  = s1 + 256;
    k_pre<<<2048, 256, 0, stream>>>(x, nb, W1, W2, Wc, Wcb, zbf, s1, s2);
    k_adj<<<NB * NC, 256, 0, stream>>>(x, nb, s1, s2, adj, zbf);
    k_gemm<<<1024, 256, 0, stream>>>(zbf, Wcb, out);
  } else {
    float* hws = (float*)d_ws;
    float* s1  = hws + 262144;
    float* s2  = s1 + 256;
    k_scores_fb<<<NB * NN + NB, 256, 0, stream>>>(x, nb, W1, W2, s1, s2);
    k_adj_fb<<<NB * NC, 256, 0, stream>>>(x, nb, s1, s2, adj, hws);
    k_gemm_f32<<<256, 256, 0, stream>>>(hws, x, Wc, out);
  }
}

// Round 15
// 96.838 us; speedup vs baseline: 2.0307x; 1.1241x over previous
//
#include <hip/hip_runtime.h>
#include <hip/hip_bf16.h>
#include <math.h>

// B=256, C=4, N=64, F=256, OC=8, OF=256
// d_out = out (256*2048 f32) then adj (256*4*256*256 f32).
// R15: k_gemm rebuilt as 64x64 LDS-staged tiles (traffic 256MB -> 64MB).

typedef __bf16 bf16x8 __attribute__((ext_vector_type(8)));
typedef __bf16 bf16x4 __attribute__((ext_vector_type(4)));
typedef float f32x4 __attribute__((ext_vector_type(4)));

#define NB 256
#define NC 4
#define NN 64
#define NF 256
#define NO 2048

// ============ Kernel 1: s1, s2, Wc->bf16, x->zbf (2048 blocks, grid-stride) ==
__global__ __launch_bounds__(256) void k_pre(
    const float* __restrict__ x, const float* __restrict__ nb,
    const float* __restrict__ W1, const float* __restrict__ W2,
    const float* __restrict__ Wc,
    __hip_bfloat16* __restrict__ Wcb, __hip_bfloat16* __restrict__ zbf,
    float* __restrict__ s1, float* __restrict__ s2)
{
  __shared__ float w2s[256], w1s[256];
  int t = threadIdx.x;
  int w = t >> 6, l = t & 63;

  w2s[t] = W2[t] + W2[256 + t] + W2[512 + t] + W2[768 + t];
  w1s[t] = W1[t] + W1[256 + t] + W1[512 + t] + W1[768 + t];
  __syncthreads();

  int gw = blockIdx.x * 4 + w;
  float4 wv2 = *(const float4*)&w2s[l * 4];
  float4 wv1 = *(const float4*)&w1s[l * 4];
  for (int task = gw; task < 16640; task += 8192) {
    bool isS2 = task < 16384;
    const float4* src = isS2 ? ((const float4*)nb + (size_t)task * 256)
                             : ((const float4*)x + (size_t)(task - 16384) * 256);
    float4 wv = isS2 ? wv2 : wv1;
    float val = 0.f;
    #pragma unroll
    for (int k = 0; k < 4; ++k) {
      float4 v = src[l + 64 * k];
      val += v.x * wv.x + v.y * wv.y + v.z * wv.z + v.w * wv.w;
    }
    for (int off = 32; off > 0; off >>= 1) val += __shfl_down(val, off);
    if (l == 0) {
      if (isS2) s2[task] = val;
      else s1[task - 16384] = val;
    }
  }

  for (int task = blockIdx.x; task < 4352; task += 2048) {
    if (task < 4096) {
      int idx = task * 256 + t;
      float4 v = ((const float4*)Wc)[idx];
      bf16x4 o = { (__bf16)v.x, (__bf16)v.y, (__bf16)v.z, (__bf16)v.w };
      ((bf16x4*)Wcb)[idx] = o;
    } else {
      int i = (task - 4096) * 256 + t;
      int e = i * 4;
      int b = e >> 10, r = e & 1023;
      float4 v = ((const float4*)x)[i];
      bf16x4 o = { (__bf16)v.x, (__bf16)v.y, (__bf16)v.z, (__bf16)v.w };
      *(bf16x4*)(zbf + (size_t)b * 2048 + 1024 + r) = o;
    }
  }
}

// ============ Kernel 2: adj + h (R5 structure, nt stores) ============
__global__ __launch_bounds__(256) void k_adj(
    const float* __restrict__ x, const float* __restrict__ nb,
    const float* __restrict__ s1, const float* __restrict__ s2,
    float* __restrict__ adj, __hip_bfloat16* __restrict__ zbf)
{
  __shared__ float xs[256], ns[256], invs[256], wsh[64];
  __shared__ float part[4][256];
  int t = threadIdx.x;
  int w = t >> 6, l = t & 63;
  int blk = blockIdx.x;
  int b = blk >> 2, c = blk & 3;

  if (t < 64) {
    float v = s1[b] * s2[b * 64 + t];
    float m = v;
    for (int off = 32; off > 0; off >>= 1) m = fmaxf(m, __shfl_xor(m, off));
    float e = expf(v - m);
    float s = e;
    for (int off = 32; off > 0; off >>= 1) s += __shfl_xor(s, off);
    wsh[t] = e / s;
  }
  xs[t] = x[(size_t)blk * 256 + t];
  __syncthreads();

  const float4* nb4 = (const float4*)(nb + (size_t)b * 65536 + c * 256);
  float4 a4 = {0.f, 0.f, 0.f, 0.f};
  #pragma unroll
  for (int k = 0; k < 16; ++k) {
    int n = w + 4 * k;
    float4 v = nb4[(size_t)n * 256 + l];
    float wn = wsh[n];
    a4.x = fmaf(wn, v.x, a4.x);
    a4.y = fmaf(wn, v.y, a4.y);
    a4.z = fmaf(wn, v.z, a4.z);
    a4.w = fmaf(wn, v.w, a4.w);
  }
  *(float4*)&part[w][l * 4] = a4;
  __syncthreads();
  ns[t] = part[0][t] + part[1][t] + part[2][t] + part[3][t];
  __syncthreads();

  int j0 = l * 4;
  float4 xv = *(const float4*)&xs[j0];
  float4 nv = *(const float4*)&ns[j0];
  int i0 = w * 64;

  float4 cs = {0.f, 0.f, 0.f, 0.f};
  #pragma unroll 4
  for (int ii = 0; ii < 64; ++ii) {
    int i = i0 + ii;
    float xi = xs[i], ni = ns[i];
    cs.x += __builtin_amdgcn_sqrtf(fmaxf(fabsf(fmaf(xi, nv.x, xv.x * ni)), 1e-8f));
    cs.y += __builtin_amdgcn_sqrtf(fmaxf(fabsf(fmaf(xi, nv.y, xv.y * ni)), 1e-8f));
    cs.z += __builtin_amdgcn_sqrtf(fmaxf(fabsf(fmaf(xi, nv.z, xv.z * ni)), 1e-8f));
    cs.w += __builtin_amdgcn_sqrtf(fmaxf(fabsf(fmaf(xi, nv.w, xv.w * ni)), 1e-8f));
  }
  *(float4*)&part[w][j0] = cs;
  __syncthreads();
  invs[t] = 1.f / (part[0][t] + part[1][t] + part[2][t] + part[3][t] + 1e-7f);
  __syncthreads();

  float4 iv = *(const float4*)&invs[j0];
  float4 ha = {0.f, 0.f, 0.f, 0.f};
  float* ab = adj + (size_t)blk * 65536;
  #pragma unroll 4
  for (int ii = 0; ii < 64; ++ii) {
    int i = i0 + ii;
    float xi = xs[i], ni = ns[i];
    float pix = invs[i] * xi;
    float v0 = fmaf(xi, nv.x, xv.x * ni);
    float v1 = fmaf(xi, nv.y, xv.y * ni);
    float v2 = fmaf(xi, nv.z, xv.z * ni);
    float v3 = fmaf(xi, nv.w, xv.w * ni);
    float g0 = copysignf(__builtin_amdgcn_sqrtf(fmaxf(fabsf(v0), 1e-8f)), v0);
    float g1 = copysignf(__builtin_amdgcn_sqrtf(fmaxf(fabsf(v1), 1e-8f)), v1);
    float g2 = copysignf(__builtin_amdgcn_sqrtf(fmaxf(fabsf(v2), 1e-8f)), v2);
    float g3 = copysignf(__builtin_amdgcn_sqrtf(fmaxf(fabsf(v3), 1e-8f)), v3);
    f32x4 o = { g0 * iv.x, g1 * iv.y, g2 * iv.z, g3 * iv.w };
    __builtin_nontemporal_store(o, (f32x4*)&ab[(size_t)i * 256 + j0]);
    ha.x = fmaf(g0, pix, ha.x);
    ha.y = fmaf(g1, pix, ha.y);
    ha.z = fmaf(g2, pix, ha.z);
    ha.w = fmaf(g3, pix, ha.w);
  }
  __syncthreads();
  *(float4*)&part[w][j0] = ha;
  __syncthreads();
  float hsum = part[0][t] + part[1][t] + part[2][t] + part[3][t];
  zbf[(size_t)b * 2048 + c * 256 + t] = __float2bfloat16(hsum);
}

// ============ Kernel 3: out = Z @ Wc^T — 64x64 LDS-staged tiles ============
// 128 blocks x 256 thr (4 waves). bm=id&3 (m-tile 64), bn=id>>2 (n-tile 64).
// Wave w: quadrant (mh=w>>1, nh=w&1) of 32x32 = 2x2 MFMA tiles.
// BK=128: stage A[64][128] + B[64][128] bf16 (rows padded +8) per step; 16 steps.
// Global traffic: Z x32 + Wcb x4 = 64 MB (vs 256 MB at 32x32 direct).
__global__ __launch_bounds__(256) void k_gemm(
    const __hip_bfloat16* __restrict__ zb, const __hip_bfloat16* __restrict__ Wcb,
    float* __restrict__ out)
{
  __shared__ __hip_bfloat16 Al[64][136];
  __shared__ __hip_bfloat16 Bl[64][136];
  int t = threadIdx.x;
  int wave = t >> 6, lane = t & 63;
  int g = lane >> 4, r = lane & 15;
  int mh = wave >> 1, nh = wave & 1;
  int bm = blockIdx.x & 3, bn = blockIdx.x >> 2;

  f32x4 acc00 = {0.f,0.f,0.f,0.f}, acc01 = {0.f,0.f,0.f,0.f};
  f32x4 acc10 = {0.f,0.f,0.f,0.f}, acc11 = {0.f,0.f,0.f,0.f};

  const float4* zb4 = (const float4*)zb;    // 256 float4 per 2048-bf16 row
  const float4* wc4 = (const float4*)Wcb;

  for (int kb = 0; kb < 16; ++kb) {
    #pragma unroll
    for (int q = 0; q < 4; ++q) {
      int idx = q * 256 + t;                // coalesced: consecutive t -> consecutive f4
      int row = idx >> 4, c16 = idx & 15;
      float4 va = zb4[(size_t)(bm * 64 + row) * 256 + kb * 16 + c16];
      *(float4*)&Al[row][c16 * 8] = va;
      float4 vb = wc4[(size_t)(bn * 64 + row) * 256 + kb * 16 + c16];
      *(float4*)&Bl[row][c16 * 8] = vb;
    }
    __syncthreads();
    #pragma unroll
    for (int kk = 0; kk < 4; ++kk) {
      bf16x8 a0 = *(const bf16x8*)&Al[mh * 32 + r][kk * 32 + g * 8];
      bf16x8 a1 = *(const bf16x8*)&Al[mh * 32 + 16 + r][kk * 32 + g * 8];
      bf16x8 b0 = *(const bf16x8*)&Bl[nh * 32 + r][kk * 32 + g * 8];
      bf16x8 b1 = *(const bf16x8*)&Bl[nh * 32 + 16 + r][kk * 32 + g * 8];
      acc00 = __builtin_amdgcn_mfma_f32_16x16x32_bf16(a0, b0, acc00, 0, 0, 0);
      acc01 = __builtin_amdgcn_mfma_f32_16x16x32_bf16(a0, b1, acc01, 0, 0, 0);
      acc10 = __builtin_amdgcn_mfma_f32_16x16x32_bf16(a1, b0, acc10, 0, 0, 0);
      acc11 = __builtin_amdgcn_mfma_f32_16x16x32_bf16(a1, b1, acc11, 0, 0, 0);
    }
    __syncthreads();
  }

  int row0 = bm * 64 + mh * 32 + g * 4;
  int col0 = bn * 64 + nh * 32 + r;
  #pragma unroll
  for (int q = 0; q < 4; ++q) {
    __builtin_nontemporal_store(acc00[q], &out[(size_t)(row0 + q) * 2048 + col0]);
    __builtin_nontemporal_store(acc01[q], &out[(size_t)(row0 + q) * 2048 + col0 + 16]);
    __builtin_nontemporal_store(acc10[q], &out[(size_t)(row0 + 16 + q) * 2048 + col0]);
    __builtin_nontemporal_store(acc11[q], &out[(size_t)(row0 + 16 + q) * 2048 + col0 + 16]);
  }
}

// ================= Fallback path (small ws) =================
__global__ __launch_bounds__(256) void k_scores_fb(
    const float* __restrict__ x, const float* __restrict__ nb,
    const float* __restrict__ W1, const float* __restrict__ W2,
    float* __restrict__ s1, float* __restrict__ s2)
{
  __shared__ float red[4];
  int t = threadIdx.x;
  int gid = blockIdx.x;
  float val;
  if (gid < NB * NN) {
    float w = W2[t] + W2[256 + t] + W2[512 + t] + W2[768 + t];
    const float* p = nb + (size_t)gid * 1024;
    val = w * (p[t] + p[256 + t] + p[512 + t] + p[768 + t]);
  } else {
    int b = gid - NB * NN;
    float w = W1[t] + W1[256 + t] + W1[512 + t] + W1[768 + t];
    const float* p = x + (size_t)b * 1024;
    val = w * (p[t] + p[256 + t] + p[512 + t] + p[768 + t]);
  }
  for (int off = 32; off > 0; off >>= 1) val += __shfl_down(val, off);
  if ((t & 63) == 0) red[t >> 6] = val;
  __syncthreads();
  if (t == 0) {
    float s = red[0] + red[1] + red[2] + red[3];
    if (gid < NB * NN) s2[gid] = s;
    else s1[gid - NB * NN] = s;
  }
}

__global__ __launch_bounds__(256) void k_adj_fb(
    const float* __restrict__ x, const float* __restrict__ nb,
    const float* __restrict__ s1, const float* __restrict__ s2,
    float* __restrict__ adj, float* __restrict__ hf)
{
  __shared__ float xs[256], ns[256], invs[256], wsh[64];
  __shared__ float part[4][256];
  int t = threadIdx.x;
  int w = t >> 6, l = t & 63;
  int blk = blockIdx.x;
  int b = blk >> 2, c = blk & 3;

  if (t < 64) {
    float v = s1[b] * s2[b * 64 + t];
    float m = v;
    for (int off = 32; off > 0; off >>= 1) m = fmaxf(m, __shfl_xor(m, off));
    float e = expf(v - m);
    float s = e;
    for (int off = 32; off > 0; off >>= 1) s += __shfl_xor(s, off);
    wsh[t] = e / s;
  }
  __syncthreads();
  float acc = 0.f;
  const float* pb = nb + (size_t)b * 65536 + c * 256 + t;
  #pragma unroll 8
  for (int n = 0; n < 64; ++n) acc = fmaf(wsh[n], pb[(size_t)n * 1024], acc);
  ns[t] = acc;
  xs[t] = x[(size_t)blk * 256 + t];
  __syncthreads();

  int j0 = l * 4;
  float4 xv = *(const float4*)&xs[j0];
  float4 nv = *(const float4*)&ns[j0];
  int i0 = w * 64;
  float4 cs = {0.f, 0.f, 0.f, 0.f};
  for (int ii = 0; ii < 64; ++ii) {
    int i = i0 + ii;
    float xi = xs[i], ni = ns[i];
    cs.x += __builtin_amdgcn_sqrtf(fmaxf(fabsf(fmaf(xi, nv.x, xv.x * ni)), 1e-8f));
    cs.y += __builtin_amdgcn_sqrtf(fmaxf(fabsf(fmaf(xi, nv.y, xv.y * ni)), 1e-8f));
    cs.z += __builtin_amdgcn_sqrtf(fmaxf(fabsf(fmaf(xi, nv.z, xv.z * ni)), 1e-8f));
    cs.w += __builtin_amdgcn_sqrtf(fmaxf(fabsf(fmaf(xi, nv.w, xv.w * ni)), 1e-8f));
  }
  *(float4*)&part[w][j0] = cs;
  __syncthreads();
  invs[t] = 1.f / (part[0][t] + part[1][t] + part[2][t] + part[3][t] + 1e-7f);
  __syncthreads();

  float4 iv = *(const float4*)&invs[j0];
  float4 ha = {0.f, 0.f, 0.f, 0.f};
  float* ab = adj + (size_t)blk * 65536;
  for (int ii = 0; ii < 64; ++ii) {
    int i = i0 + ii;
    float xi = xs[i], ni = ns[i];
    float pix = invs[i] * xi;
    float v0 = fmaf(xi, nv.x, xv.x * ni);
    float v1 = fmaf(xi, nv.y, xv.y * ni);
    float v2 = fmaf(xi, nv.z, xv.z * ni);
    float v3 = fmaf(xi, nv.w, xv.w * ni);
    float g0 = copysignf(__builtin_amdgcn_sqrtf(fmaxf(fabsf(v0), 1e-8f)), v0);
    float g1 = copysignf(__builtin_amdgcn_sqrtf(fmaxf(fabsf(v1), 1e-8f)), v1);
    float g2 = copysignf(__builtin_amdgcn_sqrtf(fmaxf(fabsf(v2), 1e-8f)), v2);
    float g3 = copysignf(__builtin_amdgcn_sqrtf(fmaxf(fabsf(v3), 1e-8f)), v3);
    f32x4 o = { g0 * iv.x, g1 * iv.y, g2 * iv.z, g3 * iv.w };
    *(f32x4*)&ab[(size_t)i * 256 + j0] = o;
    ha.x = fmaf(g0, pix, ha.x);
    ha.y = fmaf(g1, pix, ha.y);
    ha.z = fmaf(g2, pix, ha.z);
    ha.w = fmaf(g3, pix, ha.w);
  }
  __syncthreads();
  *(float4*)&part[w][j0] = ha;
  __syncthreads();
  hf[(size_t)blk * 256 + t] = part[0][t] + part[1][t] + part[2][t] + part[3][t];
}

__device__ inline bf16x8 cvt8_p(const float* p) {
  const float4* q = reinterpret_cast<const float4*>(p);
  float4 a = q[0], bq = q[1];
  bf16x8 r;
  r[0] = (__bf16)a.x;  r[1] = (__bf16)a.y;  r[2] = (__bf16)a.z;  r[3] = (__bf16)a.w;
  r[4] = (__bf16)bq.x; r[5] = (__bf16)bq.y; r[6] = (__bf16)bq.z; r[7] = (__bf16)bq.w;
  return r;
}

__global__ __launch_bounds__(256) void k_gemm_f32(
    const float* __restrict__ h, const float* __restrict__ x,
    const float* __restrict__ Wc, float* __restrict__ out)
{
  int tid = threadIdx.x;
  int wave = tid >> 6, lane = tid & 63;
  int g = lane >> 4, r = lane & 15;
  int bm = blockIdx.x & 3, bn = blockIdx.x >> 2;
  int m0 = bm * 64 + wave * 16;
  int n0 = bn * 32;
  int arow = m0 + r;
  int koff = g * 8;

  const float* za = h + (size_t)arow * 1024 + koff;
  const float* zb = x + (size_t)arow * 1024 + koff;
  const float* w0 = Wc + (size_t)(n0 + r) * 2048 + koff;
  const float* w1 = Wc + (size_t)(n0 + 16 + r) * 2048 + koff;

  f32x4 acc0 = {0.f, 0.f, 0.f, 0.f}, acc1 = {0.f, 0.f, 0.f, 0.f};
  #pragma unroll 4
  for (int ks = 0; ks < 32; ++ks) {
    acc0 = __builtin_amdgcn_mfma_f32_16x16x32_bf16(cvt8_p(za + ks * 32), cvt8_p(w0 + ks * 32), acc0, 0, 0, 0);
    acc1 = __builtin_amdgcn_mfma_f32_16x16x32_bf16(cvt8_p(za + ks * 32), cvt8_p(w1 + ks * 32), acc1, 0, 0, 0);
  }
  #pragma unroll 4
  for (int ks = 0; ks < 32; ++ks) {
    acc0 = __builtin_amdgcn_mfma_f32_16x16x32_bf16(cvt8_p(zb + ks * 32), cvt8_p(w0 + 1024 + ks * 32), acc0, 0, 0, 0);
    acc1 = __builtin_amdgcn_mfma_f32_16x16x32_bf16(cvt8_p(zb + ks * 32), cvt8_p(w1 + 1024 + ks * 32), acc1, 0, 0, 0);
  }
  #pragma unroll
  for (int q = 0; q < 4; ++q) {
    int row = m0 + g * 4 + q;
    out[(size_t)row * 2048 + n0 + r]      = acc0[q];
    out[(size_t)row * 2048 + n0 + 16 + r] = acc1[q];
  }
}

extern "C" void kernel_launch(void* const* d_in, const int* in_sizes, int n_in,
                              void* d_out, int out_size, void* d_ws, size_t ws_size,
                              hipStream_t stream) {
  const float* x  = (const float*)d_in[0];
  const float* nb = (const float*)d_in[1];
  const float* W1 = (const float*)d_in[2];
  const float* W2 = (const float*)d_in[3];
  const float* Wc = (const float*)d_in[4];
  float* out = (float*)d_out;
  float* adj = out + (size_t)NB * NO;

  char* ws = (char*)d_ws;
  const size_t ZBF_B = 1048576;        // 256*2048 bf16
  const size_t WCB_B = 8388608;        // 2048*2048 bf16
  const size_t FREG = (256 + 16384) * 4;
  bool fast = ws_size >= ZBF_B + WCB_B + FREG;

  if (fast) {
    __hip_bfloat16* zbf = (__hip_bfloat16*)ws;
    __hip_bfloat16* Wcb = (__hip_bfloat16*)(ws + ZBF_B);
    float* s1  = (float*)(ws + ZBF_B + WCB_B);
    float* s2  = s1 + 256;
    k_pre<<<2048, 256, 0, stream>>>(x, nb, W1, W2, Wc, Wcb, zbf, s1, s2);
    k_adj<<<NB * NC, 256, 0, stream>>>(x, nb, s1, s2, adj, zbf);
    k_gemm<<<128, 256, 0, stream>>>(zbf, Wcb, out);
  } else {
    float* hws = (float*)d_ws;
    float* s1  = hws + 262144;
    float* s2  = s1 + 256;
    k_scores_fb<<<NB * NN + NB, 256, 0, stream>>>(x, nb, W1, W2, s1, s2);
    k_adj_fb<<<NB * NC, 256, 0, stream>>>(x, nb, s1, s2, adj, hws);
    k_gemm_f32<<<256, 256, 0, stream>>>(hws, x, Wc, out);
  }
}

// Round 16
// 94.545 us; speedup vs baseline: 2.0799x; 1.0243x over previous
//
#include <hip/hip_runtime.h>
#include <hip/hip_bf16.h>
#include <math.h>

// B=256, C=4, N=64, F=256, OC=8, OF=256
// d_out = out (256*2048 f32) then adj (256*4*256*256 f32).
// R16: (1) Wc/x cvt folded into k_adj front (memory work under VALU phase);
//      k_pre = scores only. (2) k_gemm double-buffered LDS staging.

typedef __bf16 bf16x8 __attribute__((ext_vector_type(8)));
typedef __bf16 bf16x4 __attribute__((ext_vector_type(4)));
typedef float f32x4 __attribute__((ext_vector_type(4)));

#define NB 256
#define NC 4
#define NN 64
#define NF 256
#define NO 2048

// ============ Kernel 1: s1, s2 only (2048 blocks, wave-granular tasks) ======
__global__ __launch_bounds__(256) void k_pre(
    const float* __restrict__ x, const float* __restrict__ nb,
    const float* __restrict__ W1, const float* __restrict__ W2,
    float* __restrict__ s1, float* __restrict__ s2)
{
  __shared__ float w2s[256], w1s[256];
  int t = threadIdx.x;
  int w = t >> 6, l = t & 63;

  w2s[t] = W2[t] + W2[256 + t] + W2[512 + t] + W2[768 + t];
  w1s[t] = W1[t] + W1[256 + t] + W1[512 + t] + W1[768 + t];
  __syncthreads();

  int gw = blockIdx.x * 4 + w;
  float4 wv2 = *(const float4*)&w2s[l * 4];
  float4 wv1 = *(const float4*)&w1s[l * 4];
  for (int task = gw; task < 16640; task += 8192) {
    bool isS2 = task < 16384;
    const float4* src = isS2 ? ((const float4*)nb + (size_t)task * 256)
                             : ((const float4*)x + (size_t)(task - 16384) * 256);
    float4 wv = isS2 ? wv2 : wv1;
    float val = 0.f;
    #pragma unroll
    for (int k = 0; k < 4; ++k) {
      float4 v = src[l + 64 * k];
      val += v.x * wv.x + v.y * wv.y + v.z * wv.z + v.w * wv.w;
    }
    for (int off = 32; off > 0; off >>= 1) val += __shfl_down(val, off);
    if (l == 0) {
      if (isS2) s2[task] = val;
      else s1[task - 16384] = val;
    }
  }
}

// ============ Kernel 2: adj + h + (Wc,x)->bf16 cvt prologue ============
// One block per (b,c). cvt slice = fire-and-forget memory work that fills the
// otherwise idle memory pipe during the VALU-bound front (softmax/gather/pass1).
__global__ __launch_bounds__(256) void k_adj(
    const float* __restrict__ x, const float* __restrict__ nb,
    const float* __restrict__ Wc,
    const float* __restrict__ s1, const float* __restrict__ s2,
    float* __restrict__ adj, __hip_bfloat16* __restrict__ zbf,
    __hip_bfloat16* __restrict__ Wcb)
{
  __shared__ float xs[256], ns[256], invs[256], wsh[64];
  __shared__ float part[4][256];
  int t = threadIdx.x;
  int w = t >> 6, l = t & 63;
  int blk = blockIdx.x;
  int b = blk >> 2, c = blk & 3;

  // --- cvt prologue: this block's 1024-f4 slice of Wc (all blocks = 16MB) ---
  {
    const float4* Wc4 = (const float4*)Wc;
    bf16x4* Wcb4 = (bf16x4*)Wcb;
    #pragma unroll
    for (int q = 0; q < 4; ++q) {
      int idx = blk * 1024 + q * 256 + t;
      float4 v = Wc4[idx];
      bf16x4 o = { (__bf16)v.x, (__bf16)v.y, (__bf16)v.z, (__bf16)v.w };
      Wcb4[idx] = o;
    }
  }

  if (t < 64) {
    float v = s1[b] * s2[b * 64 + t];
    float m = v;
    for (int off = 32; off > 0; off >>= 1) m = fmaxf(m, __shfl_xor(m, off));
    float e = expf(v - m);
    float s = e;
    for (int off = 32; off > 0; off >>= 1) s += __shfl_xor(s, off);
    wsh[t] = e / s;
  }
  float xval = x[(size_t)blk * 256 + t];
  xs[t] = xval;
  zbf[(size_t)b * 2048 + 1024 + c * 256 + t] = __float2bfloat16(xval);  // x-half of Z
  __syncthreads();

  const float4* nb4 = (const float4*)(nb + (size_t)b * 65536 + c * 256);
  float4 a4 = {0.f, 0.f, 0.f, 0.f};
  #pragma unroll
  for (int k = 0; k < 16; ++k) {
    int n = w + 4 * k;
    float4 v = nb4[(size_t)n * 256 + l];
    float wn = wsh[n];
    a4.x = fmaf(wn, v.x, a4.x);
    a4.y = fmaf(wn, v.y, a4.y);
    a4.z = fmaf(wn, v.z, a4.z);
    a4.w = fmaf(wn, v.w, a4.w);
  }
  *(float4*)&part[w][l * 4] = a4;
  __syncthreads();
  ns[t] = part[0][t] + part[1][t] + part[2][t] + part[3][t];
  __syncthreads();

  int j0 = l * 4;
  float4 xv = *(const float4*)&xs[j0];
  float4 nv = *(const float4*)&ns[j0];
  int i0 = w * 64;

  float4 cs = {0.f, 0.f, 0.f, 0.f};
  #pragma unroll 4
  for (int ii = 0; ii < 64; ++ii) {
    int i = i0 + ii;
    float xi = xs[i], ni = ns[i];
    cs.x += __builtin_amdgcn_sqrtf(fmaxf(fabsf(fmaf(xi, nv.x, xv.x * ni)), 1e-8f));
    cs.y += __builtin_amdgcn_sqrtf(fmaxf(fabsf(fmaf(xi, nv.y, xv.y * ni)), 1e-8f));
    cs.z += __builtin_amdgcn_sqrtf(fmaxf(fabsf(fmaf(xi, nv.z, xv.z * ni)), 1e-8f));
    cs.w += __builtin_amdgcn_sqrtf(fmaxf(fabsf(fmaf(xi, nv.w, xv.w * ni)), 1e-8f));
  }
  *(float4*)&part[w][j0] = cs;
  __syncthreads();
  invs[t] = 1.f / (part[0][t] + part[1][t] + part[2][t] + part[3][t] + 1e-7f);
  __syncthreads();

  float4 iv = *(const float4*)&invs[j0];
  float4 ha = {0.f, 0.f, 0.f, 0.f};
  float* ab = adj + (size_t)blk * 65536;
  #pragma unroll 4
  for (int ii = 0; ii < 64; ++ii) {
    int i = i0 + ii;
    float xi = xs[i], ni = ns[i];
    float pix = invs[i] * xi;
    float v0 = fmaf(xi, nv.x, xv.x * ni);
    float v1 = fmaf(xi, nv.y, xv.y * ni);
    float v2 = fmaf(xi, nv.z, xv.z * ni);
    float v3 = fmaf(xi, nv.w, xv.w * ni);
    float g0 = copysignf(__builtin_amdgcn_sqrtf(fmaxf(fabsf(v0), 1e-8f)), v0);
    float g1 = copysignf(__builtin_amdgcn_sqrtf(fmaxf(fabsf(v1), 1e-8f)), v1);
    float g2 = copysignf(__builtin_amdgcn_sqrtf(fmaxf(fabsf(v2), 1e-8f)), v2);
    float g3 = copysignf(__builtin_amdgcn_sqrtf(fmaxf(fabsf(v3), 1e-8f)), v3);
    f32x4 o = { g0 * iv.x, g1 * iv.y, g2 * iv.z, g3 * iv.w };
    __builtin_nontemporal_store(o, (f32x4*)&ab[(size_t)i * 256 + j0]);
    ha.x = fmaf(g0, pix, ha.x);
    ha.y = fmaf(g1, pix, ha.y);
    ha.z = fmaf(g2, pix, ha.z);
    ha.w = fmaf(g3, pix, ha.w);
  }
  __syncthreads();
  *(float4*)&part[w][j0] = ha;
  __syncthreads();
  float hsum = part[0][t] + part[1][t] + part[2][t] + part[3][t];
  zbf[(size_t)b * 2048 + c * 256 + t] = __float2bfloat16(hsum);
}

// ============ Kernel 3: out = Z @ Wc^T — 64x64 LDS tiles, double-buffered ====
// 128 blocks x 256 thr. Per k-step: issue next-tile loads -> MFMA current ->
// ds_write next -> one barrier. Hides L2/L3 latency at 1 block/CU.
__global__ __launch_bounds__(256) void k_gemm(
    const __hip_bfloat16* __restrict__ zb, const __hip_bfloat16* __restrict__ Wcb,
    float* __restrict__ out)
{
  __shared__ __hip_bfloat16 Al[2][64][136];
  __shared__ __hip_bfloat16 Bl[2][64][136];
  int t = threadIdx.x;
  int wave = t >> 6, lane = t & 63;
  int g = lane >> 4, r = lane & 15;
  int mh = wave >> 1, nh = wave & 1;
  int bm = blockIdx.x & 3, bn = blockIdx.x >> 2;

  f32x4 acc00 = {0.f,0.f,0.f,0.f}, acc01 = {0.f,0.f,0.f,0.f};
  f32x4 acc10 = {0.f,0.f,0.f,0.f}, acc11 = {0.f,0.f,0.f,0.f};

  const float4* zb4 = (const float4*)zb;
  const float4* wc4 = (const float4*)Wcb;

  // preload kb=0 into buf 0
  #pragma unroll
  for (int q = 0; q < 4; ++q) {
    int idx = q * 256 + t;
    int row = idx >> 4, c16 = idx & 15;
    float4 va = zb4[(size_t)(bm * 64 + row) * 256 + c16];
    *(float4*)&Al[0][row][c16 * 8] = va;
    float4 vb = wc4[(size_t)(bn * 64 + row) * 256 + c16];
    *(float4*)&Bl[0][row][c16 * 8] = vb;
  }
  __syncthreads();

  int cur = 0;
  for (int kb = 0; kb < 16; ++kb) {
    float4 va[4], vb[4];
    if (kb < 15) {
      #pragma unroll
      for (int q = 0; q < 4; ++q) {
        int idx = q * 256 + t;
        int row = idx >> 4, c16 = idx & 15;
        va[q] = zb4[(size_t)(bm * 64 + row) * 256 + (kb + 1) * 16 + c16];
        vb[q] = wc4[(size_t)(bn * 64 + row) * 256 + (kb + 1) * 16 + c16];
      }
    }
    #pragma unroll
    for (int kk = 0; kk < 4; ++kk) {
      bf16x8 a0 = *(const bf16x8*)&Al[cur][mh * 32 + r][kk * 32 + g * 8];
      bf16x8 a1 = *(const bf16x8*)&Al[cur][mh * 32 + 16 + r][kk * 32 + g * 8];
      bf16x8 b0 = *(const bf16x8*)&Bl[cur][nh * 32 + r][kk * 32 + g * 8];
      bf16x8 b1 = *(const bf16x8*)&Bl[cur][nh * 32 + 16 + r][kk * 32 + g * 8];
      acc00 = __builtin_amdgcn_mfma_f32_16x16x32_bf16(a0, b0, acc00, 0, 0, 0);
      acc01 = __builtin_amdgcn_mfma_f32_16x16x32_bf16(a0, b1, acc01, 0, 0, 0);
      acc10 = __builtin_amdgcn_mfma_f32_16x16x32_bf16(a1, b0, acc10, 0, 0, 0);
      acc11 = __builtin_amdgcn_mfma_f32_16x16x32_bf16(a1, b1, acc11, 0, 0, 0);
    }
    if (kb < 15) {
      #pragma unroll
      for (int q = 0; q < 4; ++q) {
        int idx = q * 256 + t;
        int row = idx >> 4, c16 = idx & 15;
        *(float4*)&Al[cur ^ 1][row][c16 * 8] = va[q];
        *(float4*)&Bl[cur ^ 1][row][c16 * 8] = vb[q];
      }
    }
    __syncthreads();
    cur ^= 1;
  }

  int row0 = bm * 64 + mh * 32 + g * 4;
  int col0 = bn * 64 + nh * 32 + r;
  #pragma unroll
  for (int q = 0; q < 4; ++q) {
    __builtin_nontemporal_store(acc00[q], &out[(size_t)(row0 + q) * 2048 + col0]);
    __builtin_nontemporal_store(acc01[q], &out[(size_t)(row0 + q) * 2048 + col0 + 16]);
    __builtin_nontemporal_store(acc10[q], &out[(size_t)(row0 + 16 + q) * 2048 + col0]);
    __builtin_nontemporal_store(acc11[q], &out[(size_t)(row0 + 16 + q) * 2048 + col0 + 16]);
  }
}

// ================= Fallback path (small ws) =================
__global__ __launch_bounds__(256) void k_scores_fb(
    const float* __restrict__ x, const float* __restrict__ nb,
    const float* __restrict__ W1, const float* __restrict__ W2,
    float* __restrict__ s1, float* __restrict__ s2)
{
  __shared__ float red[4];
  int t = threadIdx.x;
  int gid = blockIdx.x;
  float val;
  if (gid < NB * NN) {
    float w = W2[t] + W2[256 + t] + W2[512 + t] + W2[768 + t];
    const float* p = nb + (size_t)gid * 1024;
    val = w * (p[t] + p[256 + t] + p[512 + t] + p[768 + t]);
  } else {
    int b = gid - NB * NN;
    float w = W1[t] + W1[256 + t] + W1[512 + t] + W1[768 + t];
    const float* p = x + (size_t)b * 1024;
    val = w * (p[t] + p[256 + t] + p[512 + t] + p[768 + t]);
  }
  for (int off = 32; off > 0; off >>= 1) val += __shfl_down(val, off);
  if ((t & 63) == 0) red[t >> 6] = val;
  __syncthreads();
  if (t == 0) {
    float s = red[0] + red[1] + red[2] + red[3];
    if (gid < NB * NN) s2[gid] = s;
    else s1[gid - NB * NN] = s;
  }
}

__global__ __launch_bounds__(256) void k_adj_fb(
    const float* __restrict__ x, const float* __restrict__ nb,
    const float* __restrict__ s1, const float* __restrict__ s2,
    float* __restrict__ adj, float* __restrict__ hf)
{
  __shared__ float xs[256], ns[256], invs[256], wsh[64];
  __shared__ float part[4][256];
  int t = threadIdx.x;
  int w = t >> 6, l = t & 63;
  int blk = blockIdx.x;
  int b = blk >> 2, c = blk & 3;

  if (t < 64) {
    float v = s1[b] * s2[b * 64 + t];
    float m = v;
    for (int off = 32; off > 0; off >>= 1) m = fmaxf(m, __shfl_xor(m, off));
    float e = expf(v - m);
    float s = e;
    for (int off = 32; off > 0; off >>= 1) s += __shfl_xor(s, off);
    wsh[t] = e / s;
  }
  __syncthreads();
  float acc = 0.f;
  const float* pb = nb + (size_t)b * 65536 + c * 256 + t;
  #pragma unroll 8
  for (int n = 0; n < 64; ++n) acc = fmaf(wsh[n], pb[(size_t)n * 1024], acc);
  ns[t] = acc;
  xs[t] = x[(size_t)blk * 256 + t];
  __syncthreads();

  int j0 = l * 4;
  float4 xv = *(const float4*)&xs[j0];
  float4 nv = *(const float4*)&ns[j0];
  int i0 = w * 64;
  float4 cs = {0.f, 0.f, 0.f, 0.f};
  for (int ii = 0; ii < 64; ++ii) {
    int i = i0 + ii;
    float xi = xs[i], ni = ns[i];
    cs.x += __builtin_amdgcn_sqrtf(fmaxf(fabsf(fmaf(xi, nv.x, xv.x * ni)), 1e-8f));
    cs.y += __builtin_amdgcn_sqrtf(fmaxf(fabsf(fmaf(xi, nv.y, xv.y * ni)), 1e-8f));
    cs.z += __builtin_amdgcn_sqrtf(fmaxf(fabsf(fmaf(xi, nv.z, xv.z * ni)), 1e-8f));
    cs.w += __builtin_amdgcn_sqrtf(fmaxf(fabsf(fmaf(xi, nv.w, xv.w * ni)), 1e-8f));
  }
  *(float4*)&part[w][j0] = cs;
  __syncthreads();
  invs[t] = 1.f / (part[0][t] + part[1][t] + part[2][t] + part[3][t] + 1e-7f);
  __syncthreads();

  float4 iv = *(const float4*)&invs[j0];
  float4 ha = {0.f, 0.f, 0.f, 0.f};
  float* ab = adj + (size_t)blk * 65536;
  for (int ii = 0; ii < 64; ++ii) {
    int i = i0 + ii;
    float xi = xs[i], ni = ns[i];
    float pix = invs[i] * xi;
    float v0 = fmaf(xi, nv.x, xv.x * ni);
    float v1 = fmaf(xi, nv.y, xv.y * ni);
    float v2 = fmaf(xi, nv.z, xv.z * ni);
    float v3 = fmaf(xi, nv.w, xv.w * ni);
    float g0 = copysignf(__builtin_amdgcn_sqrtf(fmaxf(fabsf(v0), 1e-8f)), v0);
    float g1 = copysignf(__builtin_amdgcn_sqrtf(fmaxf(fabsf(v1), 1e-8f)), v1);
    float g2 = copysignf(__builtin_amdgcn_sqrtf(fmaxf(fabsf(v2), 1e-8f)), v2);
    float g3 = copysignf(__builtin_amdgcn_sqrtf(fmaxf(fabsf(v3), 1e-8f)), v3);
    f32x4 o = { g0 * iv.x, g1 * iv.y, g2 * iv.z, g3 * iv.w };
    *(f32x4*)&ab[(size_t)i * 256 + j0] = o;
    ha.x = fmaf(g0, pix, ha.x);
    ha.y = fmaf(g1, pix, ha.y);
    ha.z = fmaf(g2, pix, ha.z);
    ha.w = fmaf(g3, pix, ha.w);
  }
  __syncthreads();
  *(float4*)&part[w][j0] = ha;
  __syncthreads();
  hf[(size_t)blk * 256 + t] = part[0][t] + part[1][t] + part[2][t] + part[3][t];
}

__device__ inline bf16x8 cvt8_p(const float* p) {
  const float4* q = reinterpret_cast<const float4*>(p);
  float4 a = q[0], bq = q[1];
  bf16x8 r;
  r[0] = (__bf16)a.x;  r[1] = (__bf16)a.y;  r[2] = (__bf16)a.z;  r[3] = (__bf16)a.w;
  r[4] = (__bf16)bq.x; r[5] = (__bf16)bq.y; r[6] = (__bf16)bq.z; r[7] = (__bf16)bq.w;
  return r;
}

__global__ __launch_bounds__(256) void k_gemm_f32(
    const float* __restrict__ h, const float* __restrict__ x,
    const float* __restrict__ Wc, float* __restrict__ out)
{
  int tid = threadIdx.x;
  int wave = tid >> 6, lane = tid & 63;
  int g = lane >> 4, r = lane & 15;
  int bm = blockIdx.x & 3, bn = blockIdx.x >> 2;
  int m0 = bm * 64 + wave * 16;
  int n0 = bn * 32;
  int arow = m0 + r;
  int koff = g * 8;

  const float* za = h + (size_t)arow * 1024 + koff;
  const float* zb = x + (size_t)arow * 1024 + koff;
  const float* w0 = Wc + (size_t)(n0 + r) * 2048 + koff;
  const float* w1 = Wc + (size_t)(n0 + 16 + r) * 2048 + koff;

  f32x4 acc0 = {0.f, 0.f, 0.f, 0.f}, acc1 = {0.f, 0.f, 0.f, 0.f};
  #pragma unroll 4
  for (int ks = 0; ks < 32; ++ks) {
    acc0 = __builtin_amdgcn_mfma_f32_16x16x32_bf16(cvt8_p(za + ks * 32), cvt8_p(w0 + ks * 32), acc0, 0, 0, 0);
    acc1 = __builtin_amdgcn_mfma_f32_16x16x32_bf16(cvt8_p(za + ks * 32), cvt8_p(w1 + ks * 32), acc1, 0, 0, 0);
  }
  #pragma unroll 4
  for (int ks = 0; ks < 32; ++ks) {
    acc0 = __builtin_amdgcn_mfma_f32_16x16x32_bf16(cvt8_p(zb + ks * 32), cvt8_p(w0 + 1024 + ks * 32), acc0, 0, 0, 0);
    acc1 = __builtin_amdgcn_mfma_f32_16x16x32_bf16(cvt8_p(zb + ks * 32), cvt8_p(w1 + 1024 + ks * 32), acc1, 0, 0, 0);
  }
  #pragma unroll
  for (int q = 0; q < 4; ++q) {
    int row = m0 + g * 4 + q;
    out[(size_t)row * 2048 + n0 + r]      = acc0[q];
    out[(size_t)row * 2048 + n0 + 16 + r] = acc1[q];
  }
}

extern "C" void kernel_launch(void* const* d_in, const int* in_sizes, int n_in,
                              void* d_out, int out_size, void* d_ws, size_t ws_size,
                              hipStream_t stream) {
  const float* x  = (const float*)d_in[0];
  const float* nb = (const float*)d_in[1];
  const float* W1 = (const float*)d_in[2];
  const float* W2 = (const float*)d_in[3];
  const float* Wc = (const float*)d_in[4];
  float* out = (float*)d_out;
  float* adj = out + (size_t)NB * NO;

  char* ws = (char*)d_ws;
  const size_t ZBF_B = 1048576;        // 256*2048 bf16
  const size_t WCB_B = 8388608;        // 2048*2048 bf16
  const size_t FREG = (256 + 16384) * 4;
  bool fast = ws_size >= ZBF_B + WCB_B + FREG;

  if (fast) {
    __hip_bfloat16* zbf = (__hip_bfloat16*)ws;
    __hip_bfloat16* Wcb = (__hip_bfloat16*)(ws + ZBF_B);
    float* s1  = (float*)(ws + ZBF_B + WCB_B);
    float* s2  = s1 + 256;
    k_pre<<<2048, 256, 0, stream>>>(x, nb, W1, W2, s1, s2);
    k_adj<<<NB * NC, 256, 0, stream>>>(x, nb, Wc, s1, s2, adj, zbf, Wcb);
    k_gemm<<<128, 256, 0, stream>>>(zbf, Wcb, out);
  } else {
    float* hws = (float*)d_ws;
    float* s1  = hws + 262144;
    float* s2  = s1 + 256;
    k_scores_fb<<<NB * NN + NB, 256, 0, stream>>>(x, nb, W1, W2, s1, s2);
    k_adj_fb<<<NB * NC, 256, 0, stream>>>(x, nb, s1, s2, adj, hws);
    k_gemm_f32<<<256, 256, 0, stream>>>(hws, x, Wc, out);
  }
}